// Round 1
// baseline (1774.853 us; speedup 1.0000x reference)
//
#include <hip/hip_runtime.h>
#include <hip/hip_bf16.h>
#include <math.h>

// RSM: M=1000 columns, N=4 cells/col, K=25 winners, T=64, B=128, D_IN=1024, D_OUT=1024
#define MCOL   1000
#define NCELL  4
#define TCELL  4000
#define KWIN   25
#define TT     64
#define BB     128
#define DIN    1024
#define DOUT   1024

// ---------------------------------------------------------------------------
// Generic fp32 transpose: src[R][C] -> dst[C][R]
// ---------------------------------------------------------------------------
__global__ void transpose_k(const float* __restrict__ src, float* __restrict__ dst,
                            int R, int C) {
    __shared__ float tile[32][33];
    int c0 = blockIdx.x * 32, r0 = blockIdx.y * 32;
    int tx = threadIdx.x, ty = threadIdx.y;
#pragma unroll
    for (int q = 0; q < 4; ++q) {
        int r = r0 + ty + q * 8, c = c0 + tx;
        tile[ty + q * 8][tx] = (r < R && c < C) ? src[(size_t)r * C + c] : 0.f;
    }
    __syncthreads();
#pragma unroll
    for (int q = 0; q < 4; ++q) {
        int c = c0 + ty + q * 8, r = r0 + tx;
        if (c < C && r < R) dst[(size_t)c * R + r] = tile[tx][ty + q * 8];
    }
}

// ---------------------------------------------------------------------------
// ZA = X[8192,1024] @ w_a^T  -> [8192, 1000]   (fp32 vector GEMM, 128x128x16)
// ---------------------------------------------------------------------------
__launch_bounds__(256, 2)
__global__ void za_gemm(const float* __restrict__ A,   // [8192,1024]
                        const float* __restrict__ Bw,  // [1000,1024]
                        float* __restrict__ C) {       // [8192,1000]
    __shared__ float As[16][132];
    __shared__ float Bs[16][132];
    const int i0 = blockIdx.x * 128;
    const int m0 = blockIdx.y * 128;
    const int tid = threadIdx.x;
    const int tx = tid & 15, ty = tid >> 4;
    float acc[8][8];
#pragma unroll
    for (int a = 0; a < 8; ++a)
#pragma unroll
        for (int b = 0; b < 8; ++b) acc[a][b] = 0.f;

    for (int k0 = 0; k0 < DIN; k0 += 16) {
#pragma unroll
        for (int p = 0; p < 2; ++p) {
            int f = tid + p * 256;          // 0..511 float4 slots
            int row = f >> 2, c4 = (f & 3) * 4;
            float4 v = *reinterpret_cast<const float4*>(
                &A[(size_t)(i0 + row) * DIN + k0 + c4]);
            As[c4 + 0][row] = v.x; As[c4 + 1][row] = v.y;
            As[c4 + 2][row] = v.z; As[c4 + 3][row] = v.w;
            int m = m0 + row;
            float4 w = make_float4(0.f, 0.f, 0.f, 0.f);
            if (m < MCOL)
                w = *reinterpret_cast<const float4*>(&Bw[(size_t)m * DIN + k0 + c4]);
            Bs[c4 + 0][row] = w.x; Bs[c4 + 1][row] = w.y;
            Bs[c4 + 2][row] = w.z; Bs[c4 + 3][row] = w.w;
        }
        __syncthreads();
#pragma unroll
        for (int kk = 0; kk < 16; ++kk) {
            float4 a0 = *reinterpret_cast<const float4*>(&As[kk][ty * 8]);
            float4 a1 = *reinterpret_cast<const float4*>(&As[kk][ty * 8 + 4]);
            float4 b0 = *reinterpret_cast<const float4*>(&Bs[kk][tx * 8]);
            float4 b1 = *reinterpret_cast<const float4*>(&Bs[kk][tx * 8 + 4]);
            float av[8] = {a0.x, a0.y, a0.z, a0.w, a1.x, a1.y, a1.z, a1.w};
            float bv[8] = {b0.x, b0.y, b0.z, b0.w, b1.x, b1.y, b1.z, b1.w};
#pragma unroll
            for (int ii = 0; ii < 8; ++ii)
#pragma unroll
                for (int jj = 0; jj < 8; ++jj)
                    acc[ii][jj] = fmaf(av[ii], bv[jj], acc[ii][jj]);
        }
        __syncthreads();
    }
#pragma unroll
    for (int ii = 0; ii < 8; ++ii) {
        int i = i0 + ty * 8 + ii;
#pragma unroll
        for (int jj = 0; jj < 8; ++jj) {
            int m = m0 + tx * 8 + jj;
            if (m < MCOL) C[(size_t)i * MCOL + m] = acc[ii][jj];
        }
    }
}

// ---------------------------------------------------------------------------
// Persistent recurrence kernel: 1 workgroup per batch row, 1024 threads.
// Thread m (<1000) owns column m: cells 4m..4m+3. Z/phi/psi live in registers.
// ---------------------------------------------------------------------------
__launch_bounds__(1024, 1)
__global__ void rsm_kernel(const float* __restrict__ ZA,   // [T*B, 1000]
                           const float* __restrict__ wbT,  // [4000,4000] = w_b^T
                           const float* __restrict__ wdT,  // [1000,1024] = w_d^T
                           const float* __restrict__ bd,   // [1024]
                           float* __restrict__ out) {      // [T*B, 1024]
    const int b = blockIdx.x;
    const int tid = threadIdx.x;
    const int lane = tid & 63, wid = tid >> 6;
    const bool colOwner = (tid < MCOL);

    __shared__ int   hist[16][256];
    __shared__ int   htot[256];
    __shared__ int   winflag[1024];
    __shared__ int   wscan[16];
    __shared__ int   wscan2[16];
    __shared__ int   bc[8];              // 0: b*, 1: above, 2: cand count
    __shared__ unsigned int candU[1024];
    __shared__ int   candI[1024];
    __shared__ int   wcellS[KWIN];
    __shared__ int   wcolS[KWIN];
    __shared__ float wdeltaS[KWIN];
    __shared__ float wycolS[KWIN];

    float Z4[4]   = {0.f, 0.f, 0.f, 0.f};
    float phi4[4] = {0.f, 0.f, 0.f, 0.f};
    float psi4[4] = {0.f, 0.f, 0.f, 0.f};
    const float breg = bd[tid];

    for (int t = 0; t < TT; ++t) {
        // ---- phase 1: sigma / pi / column max+argmax (registers only) ----
        float sig[4] = {0.f, 0.f, 0.f, 0.f};
        float lam = -INFINITY;
        int argn = 0;
        if (colOwner) {
            float za = ZA[(size_t)(t * BB + b) * MCOL + tid];
#pragma unroll
            for (int n = 0; n < 4; ++n) {
                sig[n] = za + Z4[n];
                float pi = sig[n] * (1.0f - phi4[n]);
                if (pi > lam) { lam = pi; argn = n; }   // first-max (strict >)
            }
        }
        // monotonic key: larger float -> larger uint; -inf for fake lanes
        unsigned int ubits = __float_as_uint(lam);
        unsigned int u = (ubits & 0x80000000u) ? ~ubits : (ubits | 0x80000000u);

        // ---- top-25 radix select (2 byte-levels + exact tie cleanup) ----
        int need = KWIN;
        int active = 1;
#pragma unroll
        for (int lev = 0; lev < 2; ++lev) {
            int mybyte = (lev == 0) ? (int)(u >> 24) : (int)((u >> 16) & 255u);
#pragma unroll
            for (int i = 0; i < 4; ++i) ((int*)hist)[tid + i * 1024] = 0;
            if (lev == 0) {
                winflag[tid] = 0;
                if (tid < 8) bc[tid] = 0;
            }
            __syncthreads();
            if (active) atomicAdd(&hist[wid][mybyte], 1);
            __syncthreads();
            if (tid < 256) {
                int s = 0;
#pragma unroll
                for (int w = 0; w < 16; ++w) s += hist[w][tid];
                htot[tid] = s;
            }
            __syncthreads();
            if (wid == 0) {
                int h0 = htot[lane * 4 + 0], h1 = htot[lane * 4 + 1];
                int h2 = htot[lane * 4 + 2], h3 = htot[lane * 4 + 3];
                int s = h0 + h1 + h2 + h3;
                int p = s;
                for (int d = 1; d < 64; d <<= 1) {
                    int q = __shfl_up(p, d);
                    if (lane >= d) p += q;
                }
                int T_all = __shfl(p, 63);
                int pexc = p - s;                 // prefix(lane*4)
                int X = T_all - need;             // max b with prefix(b) <= X
                int pr0 = pexc, pr1 = pexc + h0, pr2 = pexc + h0 + h1,
                    pr3 = pexc + h0 + h1 + h2;
                int lb = -1;
                if (pr0 <= X) lb = lane * 4 + 0;
                if (pr1 <= X) lb = lane * 4 + 1;
                if (pr2 <= X) lb = lane * 4 + 2;
                if (pr3 <= X) lb = lane * 4 + 3;
                int bmax = lb;
                for (int d = 32; d; d >>= 1) bmax = max(bmax, __shfl_xor(bmax, d));
                if (lb == bmax && lb >= 0) {
                    int k3 = bmax & 3;
                    int prb = (k3 == 0) ? pr0 : (k3 == 1) ? pr1 : (k3 == 2) ? pr2 : pr3;
                    int hb  = (k3 == 0) ? h0  : (k3 == 1) ? h1  : (k3 == 2) ? h2  : h3;
                    bc[0] = bmax;
                    bc[1] = T_all - prb - hb;     // count strictly above b*
                }
            }
            __syncthreads();
            int bstar = bc[0], above = bc[1];
            int wasActive = active;
            if (wasActive && mybyte > bstar) winflag[tid] = 1;  // definite winner
            active = wasActive && (mybyte == bstar);
            need -= above;
        }
        // candidates share the top 16 key bits; pick `need` best by (u desc, idx asc)
        if (active) {
            int s = atomicAdd(&bc[2], 1);
            candU[s] = u;
            candI[s] = tid;
        }
        __syncthreads();
        int c2 = bc[2];
        if (c2 == need) {
            if (active) winflag[tid] = 1;
        } else if (tid == 0) {
            for (int s = 0; s < need; ++s) {
                unsigned int bu = 0u; int bi = 0; int bj = -1;
                for (int j = 0; j < c2; ++j) {
                    int ci = candI[j];
                    if (ci < 0) continue;
                    unsigned int cu = candU[j];
                    if (bj < 0 || cu > bu || (cu == bu && ci < bi)) {
                        bu = cu; bi = ci; bj = j;
                    }
                }
                winflag[bi] = 1;
                candI[bj] = -1;
            }
        }
        __syncthreads();

        // ---- compact winners into slots (ordered by column index) ----
        int wf = winflag[tid];
        unsigned long long ball = __ballot(wf != 0);
        int myrank = __popcll(ball & ((1ull << lane) - 1ull));
        if (lane == 0) wscan[wid] = __popcll(ball);
        __syncthreads();
        if (tid < 16) {
            int s = 0;
            for (int w = 0; w < tid; ++w) s += wscan[w];
            wscan2[tid] = s;
        }
        __syncthreads();

        // ---- phase 3+4: winner records + trace updates (registers) ----
        if (colOwner) {
            float y = 0.f;
            if (wf) {
                y = tanhf(sig[argn]);
                int slot = wscan2[wid] + myrank;
                float pdec = 0.5f * psi4[argn];
                float pnew = fmaxf(pdec, y);
                wcellS[slot]  = tid * 4 + argn;
                wcolS[slot]   = tid;
                wdeltaS[slot] = pnew - pdec;      // 0 if y <= decayed psi
                wycolS[slot]  = fmaxf(y, 0.f);    // y_col = max over cells (others are 0)
            }
#pragma unroll
            for (int n = 0; n < 4; ++n) {
                float yn = (wf && n == argn) ? y : 0.f;
                psi4[n] = fmaxf(0.5f * psi4[n], yn);   // EPS   = 0.5
                phi4[n] = fmaxf(0.5f * phi4[n], yn);   // GAMMA = 0.5
                Z4[n] *= 0.5f;                          // exact decay of Z
            }
        }
        __syncthreads();

        // ---- phase 5: sparse rank-25 update of Z (gather w_b^T rows) ----
        if (colOwner) {
            float a0 = 0.f, a1 = 0.f, a2 = 0.f, a3 = 0.f;
#pragma unroll 5
            for (int j = 0; j < KWIN; ++j) {
                float d = wdeltaS[j];
                if (d != 0.f) {
                    const float4 w4 = *reinterpret_cast<const float4*>(
                        &wbT[(size_t)wcellS[j] * TCELL + tid * 4]);
                    a0 = fmaf(d, w4.x, a0);
                    a1 = fmaf(d, w4.y, a1);
                    a2 = fmaf(d, w4.z, a2);
                    a3 = fmaf(d, w4.w, a3);
                }
            }
            Z4[0] += a0; Z4[1] += a1; Z4[2] += a2; Z4[3] += a3;
        }

        // ---- phase 6: sparse decode out = y_col @ w_d^T + b_d ----
        {
            float s = 0.f;
#pragma unroll 5
            for (int j = 0; j < KWIN; ++j) {
                float yc = wycolS[j];
                if (yc != 0.f)
                    s = fmaf(yc, wdT[(size_t)wcolS[j] * DOUT + tid], s);
            }
            out[(size_t)(t * BB + b) * DOUT + tid] = s + breg;
        }
        // no trailing barrier needed: next step's first LDS writes (hist/winflag/bc)
        // happen only after the level-0 __syncthreads(), and phases 5/6 don't read them.
    }
}

// ---------------------------------------------------------------------------
extern "C" void kernel_launch(void* const* d_in, const int* in_sizes, int n_in,
                              void* d_out, int out_size, void* d_ws, size_t ws_size,
                              hipStream_t stream) {
    const float* x   = (const float*)d_in[0];   // [64,128,1024]
    const float* w_a = (const float*)d_in[1];   // [1000,1024]
    const float* w_b = (const float*)d_in[2];   // [4000,4000]
    const float* w_d = (const float*)d_in[3];   // [1024,1000]
    const float* b_d = (const float*)d_in[4];   // [1024]
    float* out = (float*)d_out;                  // [64,128,1024]

    // workspace layout (floats): wbT[16e6] | wdT[1.024e6] | ZA[8.192e6]
    const size_t need_bytes = (size_t)(16000000 + 1024000 + 8192000) * 4;
    if (ws_size < need_bytes) return;  // insufficient scratch: fail loudly
    float* wbT = (float*)d_ws;
    float* wdT = wbT + 16000000;
    float* ZA  = wdT + 1024000;

    transpose_k<<<dim3(125, 125), dim3(32, 8), 0, stream>>>(w_b, wbT, TCELL, TCELL);
    transpose_k<<<dim3(32, 32),  dim3(32, 8), 0, stream>>>(w_d, wdT, DOUT, MCOL);
    za_gemm<<<dim3(64, 8), 256, 0, stream>>>(x, w_a, ZA);
    rsm_kernel<<<128, 1024, 0, stream>>>(ZA, wbT, wdT, b_d, out);
}